// Round 12
// baseline (172.438 us; speedup 1.0000x reference)
//
#include <hip/hip_runtime.h>
#include <hip/hip_bf16.h>
#include <stdint.h>

#define B_DIM 8
#define S_LEN 2048
#define DMODEL 2048
#define HDIM 128

typedef __attribute__((ext_vector_type(4))) float f32x4;
typedef __attribute__((ext_vector_type(8))) short bf16x8;
typedef __attribute__((ext_vector_type(4))) short bf16x4;
typedef __attribute__((ext_vector_type(4))) unsigned int u32x4;
typedef unsigned short u16;
typedef unsigned int u32;

__device__ __forceinline__ u16 f2bf(float f) {
    union { float f; u32 u; } v; v.f = f;
    u32 u = v.u;
    u32 r = (u + 0x7fffu + ((u >> 16) & 1u)) >> 16;
    return (u16)r;
}

__device__ __forceinline__ u32 pk2bf(float a, float b) {
    float2 f2; f2.x = a; f2.y = b;
    __hip_bfloat162 h = __float22bfloat162_rn(f2);
    union { __hip_bfloat162 h; u32 u; } cv; cv.h = h;
    return cv.u;
}

__device__ __forceinline__ void async_copy16(u16* lds, const u16* g) {
    __builtin_amdgcn_global_load_lds((const __attribute__((address_space(1))) u32*)g,
                                     (__attribute__((address_space(3))) u32*)lds,
                                     16, 0, 0);
}

// ---------------- pack weights: transpose [2048 k][128 h] fp32 x3 -> bf16 Wp[384 h][2048 k]
__global__ void pack_weights(const float* __restrict__ Wq, const float* __restrict__ Wk,
                             const float* __restrict__ Wv, u16* __restrict__ Wp) {
    __shared__ u16 tl[64 * 64];
    int t = threadIdx.x;
    int bx = blockIdx.x;                 // 3 w * 32 kt * 2 ht = 192
    int w = bx >> 6;
    int kt = (bx >> 1) & 31;
    int ht = bx & 1;
    int k0 = kt * 64, h0 = ht * 64;
    const float* W = (w == 0) ? Wq : ((w == 1) ? Wk : Wv);

    int kl = t >> 2, hc = t & 3;
    const float* src = W + (size_t)(k0 + kl) * HDIM + h0 + hc * 16;
#pragma unroll
    for (int half = 0; half < 2; half++) {
        bf16x8 p;
#pragma unroll
        for (int j = 0; j < 8; j++) p[j] = (short)f2bf(src[half * 8 + j]);
        int slot = hc * 2 + half;
        *(bf16x8*)((char*)tl + kl * 128 + ((slot ^ (kl & 7)) << 4)) = p;
    }
    __syncthreads();
    int hl = t >> 2, kc = t & 3;
    u16* dst = Wp + (size_t)(w * HDIM + h0 + hl) * DMODEL + k0 + kc * 16;
#pragma unroll
    for (int half = 0; half < 2; half++) {
        bf16x8 p;
#pragma unroll
        for (int j = 0; j < 8; j++) {
            int k = kc * 16 + half * 8 + j;
            p[j] = *(u16*)((char*)tl + k * 128 + (((hl >> 3) ^ (k & 7)) << 4) + (hl & 7) * 2);
        }
        *(bf16x8*)(dst + half * 8) = p;
    }
}

// ---------------- fused QKV projection GEMM: [16384,2048] @ [2048,384] (bf16 MFMA)
// DEPTH-3 COUNTED-VMCNT PIPELINE. BM=64, BN=192, BK=64, grid 512 (2 col-splits),
// 8 waves (2m x 4n, wave tile 32x48). Bs = 4-slot ring (24KB each), As = 2 buffers.
// Per phase p: issue A(p+3) reg-loads + B(p+3) DMA; s_waitcnt vmcnt(13) guarantees
// B(p) in LDS + A(p+1) in regs while 13 newer ops (2.5 phases) stay IN FLIGHT;
// 12 MFMA; ds_write A(p+1); lgkm(0)+barrier. DMA latency now has ~3 phases of slack
// vs ~0.3 in the old 1-deep pipeline (r7/r10: every phase stalled on its own DMA).
// Ledger: BK=32 = 8-way bank conflicts (r8). LDS-free = 2x slower (r9). 1-deep
// vmcnt(2) = 78us regardless of blocks/CU (r7/r10).
__launch_bounds__(512)
__global__ void qkv_gemm(const float* __restrict__ hs, const u16* __restrict__ Wp,
                         const float* __restrict__ bq, const float* __restrict__ bk,
                         const float* __restrict__ bv,
                         u16* __restrict__ Qb, u16* __restrict__ Kb, u16* __restrict__ Vt) {
    __shared__ u16 As[2][64 * 64];       // 2 x 8 KB, 16B-slot XOR swizzle
    __shared__ u16 Bs[4][192 * 64];      // 4 x 24 KB ring, swizzled

    int t = threadIdx.x;
    int wv = t >> 6, l = t & 63, lr = l & 15, lq = l >> 4;
    int wm = wv >> 2, wn = wv & 3;
    int m0 = (blockIdx.x >> 1) * 64;
    int col0 = (blockIdx.x & 1) * 192;

    f32x4 acc[2][3] = {};

    int ar = t >> 3, aq = t & 7;         // A staging: row 0..63, 8-float chunk 0..7
    const float* gA = hs + (size_t)(m0 + ar) * DMODEL + aq * 8;

    f32x4 a0[4], a1[4];                  // 4 A-prefetch register sets (ring)

#define LOAD_A(SET, K)                                                      \
    { a0[SET] = *(const f32x4*)(gA + (K)); a1[SET] = *(const f32x4*)(gA + (K) + 4); }
#define STAGE_B(K0, BUF)                                                    \
    {                                                                       \
        _Pragma("unroll")                                                   \
        for (int i = 0; i < 3; i++) {                                       \
            int c = i * 512 + t;                                            \
            int n = c >> 3, s = c & 7;                                      \
            async_copy16(&Bs[BUF][c * 8],                                   \
                         Wp + (size_t)(col0 + n) * DMODEL + (K0) + ((s ^ (n & 7)) * 8)); \
        }                                                                   \
    }
#define WRITE_A(BUF, SET)                                                   \
    {                                                                       \
        u32x4 pk;                                                           \
        pk.x = pk2bf(a0[SET][0], a0[SET][1]); pk.y = pk2bf(a0[SET][2], a0[SET][3]); \
        pk.z = pk2bf(a1[SET][0], a1[SET][1]); pk.w = pk2bf(a1[SET][2], a1[SET][3]); \
        *(u32x4*)((char*)&As[BUF][0] + ar * 128 + ((aq ^ (ar & 7)) << 4)) = pk; \
    }
#define COMPUTE(ABUF, BBUF)                                                 \
    {                                                                       \
        _Pragma("unroll")                                                   \
        for (int kk = 0; kk < 2; kk++) {                                    \
            bf16x8 afr[2], bfr[3];                                          \
            int slot = kk * 4 + lq;                                         \
            _Pragma("unroll")                                               \
            for (int mi = 0; mi < 2; mi++) {                                \
                int row = wm * 32 + mi * 16 + lr;                           \
                afr[mi] = *(bf16x8*)((char*)&As[ABUF][0] + row * 128 + ((slot ^ (row & 7)) << 4)); \
            }                                                               \
            _Pragma("unroll")                                               \
            for (int ni = 0; ni < 3; ni++) {                                \
                int row = wn * 48 + ni * 16 + lr;                           \
                bfr[ni] = *(bf16x8*)((char*)&Bs[BBUF][0] + row * 128 + ((slot ^ (row & 7)) << 4)); \
            }                                                               \
            __builtin_amdgcn_s_setprio(1);                                  \
            _Pragma("unroll")                                               \
            for (int mi = 0; mi < 2; mi++)                                  \
                _Pragma("unroll")                                           \
                for (int ni = 0; ni < 3; ni++)                              \
                    acc[mi][ni] = __builtin_amdgcn_mfma_f32_16x16x32_bf16(afr[mi], bfr[ni], acc[mi][ni], 0, 0, 0); \
            __builtin_amdgcn_s_setprio(0);                                  \
        }                                                                   \
    }
// Phase p (J = p&3): compute(p) from As[p&1]/Bs[p&3]; prefetch tile p+3.
#define PHASE(J, K0)                                                        \
    {                                                                       \
        int kN = ((K0) + ((J) + 3) * 64) & (DMODEL - 1);                    \
        LOAD_A(((J) + 3) & 3, kN);                                          \
        STAGE_B(kN, ((J) + 3) & 3);                                         \
        __builtin_amdgcn_sched_barrier(0);                                  \
        asm volatile("s_waitcnt vmcnt(13)" ::: "memory");                   \
        __builtin_amdgcn_sched_barrier(0);                                  \
        COMPUTE((J) & 1, (J) & 3);                                          \
        WRITE_A(((J) + 1) & 1, ((J) + 1) & 3);                              \
        asm volatile("s_waitcnt lgkmcnt(0)" ::: "memory");                  \
        __builtin_amdgcn_sched_barrier(0);                                  \
        __builtin_amdgcn_s_barrier();                                       \
        __builtin_amdgcn_sched_barrier(0);                                  \
    }

    // prologue: tiles 0..2 in flight in steady-state [A,B] pair order; A(0) -> As[0].
    LOAD_A(0, 0);   STAGE_B(0, 0);
    LOAD_A(1, 64);  STAGE_B(64, 1);
    LOAD_A(2, 128); STAGE_B(128, 2);
    __builtin_amdgcn_sched_barrier(0);
    asm volatile("s_waitcnt vmcnt(13)" ::: "memory");   // A(0) regs ready
    __builtin_amdgcn_sched_barrier(0);
    WRITE_A(0, 0);
    asm volatile("s_waitcnt lgkmcnt(0)" ::: "memory");
    __builtin_amdgcn_sched_barrier(0);
    __builtin_amdgcn_s_barrier();
    __builtin_amdgcn_sched_barrier(0);

    for (int it = 0; it < 8; ++it) {
        int k0 = it * 256;
        PHASE(0, k0)
        PHASE(1, k0)
        PHASE(2, k0)
        PHASE(3, k0)
    }

    // epilogue: bias; Q pre-scaled by 1/sqrt(128); V written transposed to Vt[b][h][s]
#pragma unroll
    for (int ni = 0; ni < 3; ni++) {
        int col = col0 + wn * 48 + ni * 16 + lr;
        int w = col >> 7, h = col & 127;
        const float* bp = (w == 0) ? bq : ((w == 1) ? bk : bv);
        float bias = bp[h];
#pragma unroll
        for (int mi = 0; mi < 2; mi++) {
            int row0 = m0 + wm * 32 + mi * 16 + lq * 4;
            if (w == 2) {
                int b = row0 >> 11, s0 = row0 & (S_LEN - 1);
                bf16x4 pv;
#pragma unroll
                for (int r = 0; r < 4; r++) pv[r] = (short)f2bf(acc[mi][ni][r] + bias);
                *(bf16x4*)(Vt + (size_t)(b * HDIM + h) * S_LEN + s0) = pv;
            } else {
                float scale = (w == 0) ? 0.08838834764831845f : 1.0f;
                u16* dst = (w == 0) ? Qb : Kb;
#pragma unroll
                for (int r = 0; r < 4; r++)
                    dst[(size_t)(row0 + r) * HDIM + h] = f2bf((acc[mi][ni][r] + bias) * scale);
            }
        }
    }
#undef LOAD_A
#undef STAGE_B
#undef WRITE_A
#undef COMPUTE
#undef PHASE
}

// ---------------- causal flash attention: 4 waves per block split the KV range of ONE
// 16-row Q tile (kt = wv, wv+4, ...); no barriers in main loop; LDS merge at the end.
// launch_bounds(256,3): 3 waves/EU -> ~170-reg unified cap. (256,4) capped at 128 and
// SPILLED (rounds 4-6: VGPR=64 + 23MB scratch writes). Do not raise to 4.
// Defer-max (T13, THR=8): skip the exp+rescale of o_acc unless the tile max exceeds
// the running max by >8; P values bounded by e^8.
__launch_bounds__(256, 3)
__global__ void attn(const u16* __restrict__ Qb, const u16* __restrict__ Kb,
                     const u16* __restrict__ Vt, float* __restrict__ out) {
    __shared__ char lds[33280];          // Om[4][16][128] f32 (32768) + ml[4][16][2] f32 (512)
    float* Om = (float*)lds;
    float* ml = (float*)(lds + 32768);

    int t = threadIdx.x;
    int wv = t >> 6, l = t & 63, lr = l & 15, lq = l >> 4;
    int bx = blockIdx.x;                 // 1024 = 8 b x 128 qt
    int b = bx & 7;                      // batch == XCD for KV L2 locality
    int qt = 127 - (bx >> 3);            // descending work order
    int qr0 = qt * 16;
    size_t qbase = (size_t)b * S_LEN;
    char* Pw = lds + wv * 8192;          // P tile aliases this wave's own Om region

    bf16x8 aqf[4];
#pragma unroll
    for (int kk = 0; kk < 4; kk++)
        aqf[kk] = *(const bf16x8*)(Qb + (qbase + qr0 + lr) * HDIM + kk * 32 + lq * 8);

    f32x4 o_acc[8] = {};
    float m_run[4], l_run[4];
#pragma unroll
    for (int r = 0; r < 4; r++) { m_run[r] = -1e38f; l_run[r] = 0.f; }

    int ktd = qt >> 2;                   // diagonal 64-wide tile index
    const u16* Kbase = Kb + qbase * HDIM;
    const u16* Vbase = Vt + (size_t)b * HDIM * S_LEN;

    for (int kt = wv; kt <= ktd; kt += 4) {
        int kv0 = kt * 64;

        // S = Q K^T : K fragments straight from global (L2-hit)
        f32x4 sa[4] = {};
#pragma unroll
        for (int kk = 0; kk < 4; kk++) {
            bf16x8 bk8[4];
#pragma unroll
            for (int n = 0; n < 4; n++)
                bk8[n] = *(const bf16x8*)(Kbase + (size_t)(kv0 + n * 16 + lr) * HDIM + kk * 32 + lq * 8);
            __builtin_amdgcn_s_setprio(1);
#pragma unroll
            for (int n = 0; n < 4; n++)
                sa[n] = __builtin_amdgcn_mfma_f32_16x16x32_bf16(aqf[kk], bk8[n], sa[n], 0, 0, 0);
            __builtin_amdgcn_s_setprio(0);
        }

        if (kt == ktd) {                 // causal mask on the diagonal tile
#pragma unroll
            for (int n = 0; n < 4; n++) {
                int col = kv0 + n * 16 + lr;
#pragma unroll
                for (int r = 0; r < 4; r++) {
                    int row = qr0 + lq * 4 + r;
                    if (col > row) sa[n][r] = -1e30f;
                }
            }
        }

        // online softmax with defer-max (16-lane groups own 4 q-rows each)
#pragma unroll
        for (int r = 0; r < 4; r++) {
            float mx = fmaxf(fmaxf(sa[0][r], sa[1][r]), fmaxf(sa[2][r], sa[3][r]));
#pragma unroll
            for (int off = 8; off >= 1; off >>= 1) mx = fmaxf(mx, __shfl_xor(mx, off, 64));
            if (__any(mx > m_run[r] + 8.0f)) {   // wave-uniform branch (ballot)
                float mnew = fmaxf(m_run[r], mx);
                float f = __expf(m_run[r] - mnew);
                l_run[r] *= f;
                m_run[r] = mnew;
#pragma unroll
                for (int n = 0; n < 8; n++) o_acc[n][r] *= f;
            }
            float rs = 0.f;
            int prow = lq * 4 + r;
            char* pb = Pw + prow * 128;
#pragma unroll
            for (int n = 0; n < 4; n++) {
                float e = __expf(sa[n][r] - m_run[r]);
                rs += e;
                int col = n * 16 + lr;
                *(u16*)(pb + (((col >> 3) ^ (prow & 7)) << 4) + (col & 7) * 2) = f2bf(e);
            }
#pragma unroll
            for (int off = 8; off >= 1; off >>= 1) rs += __shfl_xor(rs, off, 64);
            l_run[r] += rs;
        }

        // O += P V : V fragments straight from global (L2-hit), per-n load+MFMA
        // (per-n form, NOT batched vb8[8]: that spilled in round 4)
#pragma unroll
        for (int kk = 0; kk < 2; kk++) {
            int slot = kk * 4 + lq;
            bf16x8 pa = *(bf16x8*)(Pw + lr * 128 + ((slot ^ (lr & 7)) << 4));
            __builtin_amdgcn_s_setprio(1);
#pragma unroll
            for (int n = 0; n < 8; n++) {
                bf16x8 vb8 = *(const bf16x8*)(Vbase + (size_t)(n * 16 + lr) * S_LEN + kv0 + kk * 32 + lq * 8);
                o_acc[n] = __builtin_amdgcn_mfma_f32_16x16x32_bf16(pa, vb8, o_acc[n], 0, 0, 0);
            }
            __builtin_amdgcn_s_setprio(0);
        }
    }

    // write partials (Om[wv] overwrites this wave's P area only after its last P read)
    __builtin_amdgcn_sched_barrier(0);
#pragma unroll
    for (int n = 0; n < 8; n++)
#pragma unroll
        for (int r = 0; r < 4; r++)
            Om[wv * 2048 + (lq * 4 + r) * 128 + n * 16 + lr] = o_acc[n][r];
    if (lr == 0) {
#pragma unroll
        for (int r = 0; r < 4; r++) {
            ml[wv * 32 + (lq * 4 + r) * 2 + 0] = m_run[r];
            ml[wv * 32 + (lq * 4 + r) * 2 + 1] = l_run[r];
        }
    }
    __syncthreads();

    // merge the 4 partials: thread -> (row = t>>4, cols (t&15)*8 .. +8)
    {
        int row = t >> 4, c0 = (t & 15) * 8;
        float m4[4], l4[4];
#pragma unroll
        for (int w = 0; w < 4; w++) {
            m4[w] = ml[w * 32 + row * 2 + 0];
            l4[w] = ml[w * 32 + row * 2 + 1];
        }
        float ms = fmaxf(fmaxf(m4[0], m4[1]), fmaxf(m4[2], m4[3]));
        float wt[4], ls = 0.f;
#pragma unroll
        for (int w = 0; w < 4; w++) { wt[w] = __expf(m4[w] - ms); ls += l4[w] * wt[w]; }
        float inv = 1.0f / ls;
        f32x4 r0 = (f32x4)0.f, r1 = (f32x4)0.f;
#pragma unroll
        for (int w = 0; w < 4; w++) {
            const f32x4* Op = (const f32x4*)(Om + w * 2048 + row * 128 + c0);
            r0 += Op[0] * wt[w];
            r1 += Op[1] * wt[w];
        }
        f32x4* dst = (f32x4*)(out + (qbase + qr0 + row) * HDIM + c0);
        dst[0] = r0 * inv;
        dst[1] = r1 * inv;
    }
}

extern "C" void kernel_launch(void* const* d_in, const int* in_sizes, int n_in,
                              void* d_out, int out_size, void* d_ws, size_t ws_size,
                              hipStream_t stream) {
    const float* hs = (const float*)d_in[0];
    const float* Wq = (const float*)d_in[1];
    const float* bq = (const float*)d_in[2];
    const float* Wk = (const float*)d_in[3];
    const float* bk = (const float*)d_in[4];
    const float* Wv = (const float*)d_in[5];
    const float* bv = (const float*)d_in[6];
    float* out = (float*)d_out;

    char* ws = (char*)d_ws;
    u16* Qb = (u16*)(ws);                       // 4 MB  [16384][128] bf16 (pre-scaled)
    u16* Kb = (u16*)(ws + (size_t)(4  << 20));  // 4 MB
    u16* Vt = (u16*)(ws + (size_t)(8  << 20));  // 4 MB  [8][128][2048] (written by qkv epilogue)
    u16* Wp = (u16*)(ws + (size_t)(12 << 20));  // 1.5 MB [384][2048]

    hipLaunchKernelGGL(pack_weights, dim3(192), dim3(256), 0, stream, Wq, Wk, Wv, Wp);
    hipLaunchKernelGGL(qkv_gemm, dim3(512), dim3(512), 0, stream, hs, Wp, bq, bk, bv, Qb, Kb, Vt);
    hipLaunchKernelGGL(attn, dim3(1024), dim3(256), 0, stream, Qb, Kb, Vt, out);
}

// Round 13
// 160.576 us; speedup vs baseline: 1.0739x; 1.0739x over previous
//
#include <hip/hip_runtime.h>
#include <hip/hip_bf16.h>
#include <stdint.h>

#define B_DIM 8
#define S_LEN 2048
#define DMODEL 2048
#define HDIM 128

typedef __attribute__((ext_vector_type(4))) float f32x4;
typedef __attribute__((ext_vector_type(8))) short bf16x8;
typedef __attribute__((ext_vector_type(4))) short bf16x4;
typedef unsigned short u16;
typedef unsigned int u32;

__device__ __forceinline__ u16 f2bf(float f) {
    union { float f; u32 u; } v; v.f = f;
    u32 u = v.u;
    u32 r = (u + 0x7fffu + ((u >> 16) & 1u)) >> 16;
    return (u16)r;
}

__device__ __forceinline__ u32 pk2bf(float a, float b) {
    float2 f2; f2.x = a; f2.y = b;
    __hip_bfloat162 h = __float22bfloat162_rn(f2);
    union { __hip_bfloat162 h; u32 u; } cv; cv.h = h;
    return cv.u;
}

__device__ __forceinline__ void async_copy16(u16* lds, const u16* g) {
    __builtin_amdgcn_global_load_lds((const __attribute__((address_space(1))) u32*)g,
                                     (__attribute__((address_space(3))) u32*)lds,
                                     16, 0, 0);
}

// ---------------- pack weights: transpose [2048 k][128 h] fp32 x3 -> bf16 Wp[384 h][2048 k]
__global__ void pack_weights(const float* __restrict__ Wq, const float* __restrict__ Wk,
                             const float* __restrict__ Wv, u16* __restrict__ Wp) {
    __shared__ u16 tl[64 * 64];
    int t = threadIdx.x;
    int bx = blockIdx.x;                 // 3 w * 32 kt * 2 ht = 192
    int w = bx >> 6;
    int kt = (bx >> 1) & 31;
    int ht = bx & 1;
    int k0 = kt * 64, h0 = ht * 64;
    const float* W = (w == 0) ? Wq : ((w == 1) ? Wk : Wv);

    int kl = t >> 2, hc = t & 3;
    const float* src = W + (size_t)(k0 + kl) * HDIM + h0 + hc * 16;
#pragma unroll
    for (int half = 0; half < 2; half++) {
        bf16x8 p;
#pragma unroll
        for (int j = 0; j < 8; j++) p[j] = (short)f2bf(src[half * 8 + j]);
        int slot = hc * 2 + half;
        *(bf16x8*)((char*)tl + kl * 128 + ((slot ^ (kl & 7)) << 4)) = p;
    }
    __syncthreads();
    int hl = t >> 2, kc = t & 3;
    u16* dst = Wp + (size_t)(w * HDIM + h0 + hl) * DMODEL + k0 + kc * 16;
#pragma unroll
    for (int half = 0; half < 2; half++) {
        bf16x8 p;
#pragma unroll
        for (int j = 0; j < 8; j++) {
            int k = kc * 16 + half * 8 + j;
            p[j] = *(u16*)((char*)tl + k * 128 + (((hl >> 3) ^ (k & 7)) << 4) + (hl & 7) * 2);
        }
        *(bf16x8*)(dst + half * 8) = p;
    }
}

// ---------------- fused QKV projection GEMM: [16384,2048] @ [2048,384] (bf16 MFMA)
// B RING-3 + A-IN-REGISTERS, counted vmcnt. BM=64, BN=384 (A read once), BK=64,
// grid 256 (1 blk/CU, LDS 144KB), 8 waves (2m x 4n, wave tile 32x96), 32 phases.
// Per phase p: issue B(p+2) DMA (6 ops) + A(p+2) per-lane reg loads (8 ops);
// s_waitcnt vmcnt(14) leaves exactly those 14 in flight -> everything from phases
// <= p-1 (B(p) for compute, B(p+1) for next phase, A(p) for cvt) is guaranteed
// landed, with ~1.8 phases of DMA slack (r7's vmcnt(2) exposed the full round trip
// each phase -> 2.4us/phase; r12's vmcnt(13) with 8 ops/phase had the same bug).
// A is per-wave-private (no barrier/LDS needed); 4x wn-redundancy served by L1.
// Ledger: BK=32 bank conflicts (r8); full-LDS-free 2x slower (r9); BN=192 2blk/CU
// no gain (r10).
__launch_bounds__(512, 1)
__global__ void qkv_gemm(const float* __restrict__ hs, const u16* __restrict__ Wp,
                         const float* __restrict__ bq, const float* __restrict__ bk,
                         const float* __restrict__ bv,
                         u16* __restrict__ Qb, u16* __restrict__ Kb, u16* __restrict__ Vt) {
    __shared__ u16 Bs[3][384 * 64];      // 3 x 48 KB ring, 16B-slot XOR swizzle

    int t = threadIdx.x;
    int wv = t >> 6, l = t & 63, lr = l & 15, lq = l >> 4;
    int wm = wv >> 2, wn = wv & 3;
    int m0 = blockIdx.x * 64;

    f32x4 acc[2][6] = {};

    // per-lane A row bases (own fragments only; wave-private)
    const float* rA0 = hs + (size_t)(m0 + wm * 32 + lr) * DMODEL + lq * 8;
    const float* rA1 = rA0 + (size_t)16 * DMODEL;

    f32x4 aA[3][8];                      // 3 prefetch sets x (2 mi x 2 kk x 2 halves)

#define STAGE_B(K0, BUF)                                                    \
    {                                                                       \
        _Pragma("unroll")                                                   \
        for (int i = 0; i < 6; i++) {                                       \
            int c = i * 512 + t;                                            \
            int n = c >> 3, s = c & 7;                                      \
            async_copy16(&Bs[BUF][c * 8],                                   \
                         Wp + (size_t)n * DMODEL + (K0) + ((s ^ (n & 7)) * 8)); \
        }                                                                   \
    }
#define LOAD_A(SET, K)                                                      \
    {                                                                       \
        _Pragma("unroll")                                                   \
        for (int kk = 0; kk < 2; kk++)                                      \
            _Pragma("unroll")                                               \
            for (int h = 0; h < 2; h++) {                                   \
                aA[SET][0 + kk * 2 + h] = *(const f32x4*)(rA0 + (K) + kk * 32 + h * 4); \
                aA[SET][4 + kk * 2 + h] = *(const f32x4*)(rA1 + (K) + kk * 32 + h * 4); \
            }                                                               \
    }
#define COMPUTE(J)                                                          \
    {                                                                       \
        _Pragma("unroll")                                                   \
        for (int kk = 0; kk < 2; kk++) {                                    \
            bf16x8 afr[2], bfr[6];                                          \
            _Pragma("unroll")                                               \
            for (int mi = 0; mi < 2; mi++) {                                \
                union { bf16x8 h8; u32 w[4]; } cv;                          \
                f32x4 v0 = aA[J][mi * 4 + kk * 2 + 0];                      \
                f32x4 v1 = aA[J][mi * 4 + kk * 2 + 1];                      \
                cv.w[0] = pk2bf(v0[0], v0[1]); cv.w[1] = pk2bf(v0[2], v0[3]); \
                cv.w[2] = pk2bf(v1[0], v1[1]); cv.w[3] = pk2bf(v1[2], v1[3]); \
                afr[mi] = cv.h8;                                            \
            }                                                               \
            int slot = kk * 4 + lq;                                         \
            _Pragma("unroll")                                               \
            for (int ni = 0; ni < 6; ni++) {                                \
                int row = wn * 96 + ni * 16 + lr;                           \
                bfr[ni] = *(bf16x8*)((char*)&Bs[J][0] + row * 128 + ((slot ^ (row & 7)) << 4)); \
            }                                                               \
            __builtin_amdgcn_s_setprio(1);                                  \
            _Pragma("unroll")                                               \
            for (int mi = 0; mi < 2; mi++)                                  \
                _Pragma("unroll")                                           \
                for (int ni = 0; ni < 6; ni++)                              \
                    acc[mi][ni] = __builtin_amdgcn_mfma_f32_16x16x32_bf16(afr[mi], bfr[ni], acc[mi][ni], 0, 0, 0); \
            __builtin_amdgcn_s_setprio(0);                                  \
        }                                                                   \
    }
// Phase: tile T = KB/64 + J (KB/64 multiple of 3 -> B slot of T is J). Stage tile
// T+2 into slot (J+2)%3, load A(T+2) into set (J+2)%3, wait, compute, barrier.
#define QPHASE(KB, J)                                                       \
    {                                                                       \
        int kN = ((KB) + ((J) + 2) * 64) & (DMODEL - 1);                    \
        STAGE_B(kN, ((J) + 2) % 3);                                         \
        LOAD_A(((J) + 2) % 3, kN);                                          \
        __builtin_amdgcn_sched_barrier(0);                                  \
        asm volatile("s_waitcnt vmcnt(14) lgkmcnt(0)" ::: "memory");        \
        __builtin_amdgcn_sched_barrier(0);                                  \
        COMPUTE(J);                                                         \
        __builtin_amdgcn_sched_barrier(0);                                  \
        __builtin_amdgcn_s_barrier();                                       \
        __builtin_amdgcn_sched_barrier(0);                                  \
    }

    // prologue: tiles 0,1 in flight; drain B(0) (leave A0/B1/A1 = 22) + barrier.
    STAGE_B(0, 0);
    LOAD_A(0, 0);
    STAGE_B(64, 1);
    LOAD_A(1, 64);
    __builtin_amdgcn_sched_barrier(0);
    asm volatile("s_waitcnt vmcnt(22)" ::: "memory");
    __builtin_amdgcn_sched_barrier(0);
    __builtin_amdgcn_s_barrier();
    __builtin_amdgcn_sched_barrier(0);

    for (int it = 0; it < 10; ++it) {
        int kb = it * 192;
        QPHASE(kb, 0)
        QPHASE(kb, 1)
        QPHASE(kb, 2)
    }
    QPHASE(1920, 0)   // tile 30 (slot 0); junk prefetch wraps, unused
    QPHASE(1920, 1)   // tile 31 (slot 1)

    // epilogue: bias; Q pre-scaled by 1/sqrt(128); V written transposed to Vt[b][h][s]
#pragma unroll
    for (int ni = 0; ni < 6; ni++) {
        int col = wn * 96 + ni * 16 + lr;
        int w = col >> 7, h = col & 127;
        const float* bp = (w == 0) ? bq : ((w == 1) ? bk : bv);
        float bias = bp[h];
#pragma unroll
        for (int mi = 0; mi < 2; mi++) {
            int row0 = m0 + wm * 32 + mi * 16 + lq * 4;
            if (w == 2) {
                int b = row0 >> 11, s0 = row0 & (S_LEN - 1);
                bf16x4 pv;
#pragma unroll
                for (int r = 0; r < 4; r++) pv[r] = (short)f2bf(acc[mi][ni][r] + bias);
                *(bf16x4*)(Vt + (size_t)(b * HDIM + h) * S_LEN + s0) = pv;
            } else {
                float scale = (w == 0) ? 0.08838834764831845f : 1.0f;
                u16* dst = (w == 0) ? Qb : Kb;
#pragma unroll
                for (int r = 0; r < 4; r++)
                    dst[(size_t)(row0 + r) * HDIM + h] = f2bf((acc[mi][ni][r] + bias) * scale);
            }
        }
    }
#undef STAGE_B
#undef LOAD_A
#undef COMPUTE
#undef QPHASE
}

// ---------------- causal flash attention: 4 waves per block split the KV range of ONE
// 16-row Q tile (kt = wv, wv+4, ...); no barriers in main loop; LDS merge at the end.
// launch_bounds(256,3): 3 waves/EU -> ~170-reg unified cap. (256,4) capped at 128 and
// SPILLED (rounds 4-6: VGPR=64 + 23MB scratch writes). Do not raise to 4.
// Defer-max (T13, THR=8): skip the exp+rescale of o_acc unless the tile max exceeds
// the running max by >8; P values bounded by e^8.
__launch_bounds__(256, 3)
__global__ void attn(const u16* __restrict__ Qb, const u16* __restrict__ Kb,
                     const u16* __restrict__ Vt, float* __restrict__ out) {
    __shared__ char lds[33280];          // Om[4][16][128] f32 (32768) + ml[4][16][2] f32 (512)
    float* Om = (float*)lds;
    float* ml = (float*)(lds + 32768);

    int t = threadIdx.x;
    int wv = t >> 6, l = t & 63, lr = l & 15, lq = l >> 4;
    int bx = blockIdx.x;                 // 1024 = 8 b x 128 qt
    int b = bx & 7;                      // batch == XCD for KV L2 locality
    int qt = 127 - (bx >> 3);            // descending work order
    int qr0 = qt * 16;
    size_t qbase = (size_t)b * S_LEN;
    char* Pw = lds + wv * 8192;          // P tile aliases this wave's own Om region

    bf16x8 aqf[4];
#pragma unroll
    for (int kk = 0; kk < 4; kk++)
        aqf[kk] = *(const bf16x8*)(Qb + (qbase + qr0 + lr) * HDIM + kk * 32 + lq * 8);

    f32x4 o_acc[8] = {};
    float m_run[4], l_run[4];
#pragma unroll
    for (int r = 0; r < 4; r++) { m_run[r] = -1e38f; l_run[r] = 0.f; }

    int ktd = qt >> 2;                   // diagonal 64-wide tile index
    const u16* Kbase = Kb + qbase * HDIM;
    const u16* Vbase = Vt + (size_t)b * HDIM * S_LEN;

    for (int kt = wv; kt <= ktd; kt += 4) {
        int kv0 = kt * 64;

        // S = Q K^T : K fragments straight from global (L2-hit)
        f32x4 sa[4] = {};
#pragma unroll
        for (int kk = 0; kk < 4; kk++) {
            bf16x8 bk8[4];
#pragma unroll
            for (int n = 0; n < 4; n++)
                bk8[n] = *(const bf16x8*)(Kbase + (size_t)(kv0 + n * 16 + lr) * HDIM + kk * 32 + lq * 8);
            __builtin_amdgcn_s_setprio(1);
#pragma unroll
            for (int n = 0; n < 4; n++)
                sa[n] = __builtin_amdgcn_mfma_f32_16x16x32_bf16(aqf[kk], bk8[n], sa[n], 0, 0, 0);
            __builtin_amdgcn_s_setprio(0);
        }

        if (kt == ktd) {                 // causal mask on the diagonal tile
#pragma unroll
            for (int n = 0; n < 4; n++) {
                int col = kv0 + n * 16 + lr;
#pragma unroll
                for (int r = 0; r < 4; r++) {
                    int row = qr0 + lq * 4 + r;
                    if (col > row) sa[n][r] = -1e30f;
                }
            }
        }

        // online softmax with defer-max (16-lane groups own 4 q-rows each)
#pragma unroll
        for (int r = 0; r < 4; r++) {
            float mx = fmaxf(fmaxf(sa[0][r], sa[1][r]), fmaxf(sa[2][r], sa[3][r]));
#pragma unroll
            for (int off = 8; off >= 1; off >>= 1) mx = fmaxf(mx, __shfl_xor(mx, off, 64));
            if (__any(mx > m_run[r] + 8.0f)) {   // wave-uniform branch (ballot)
                float mnew = fmaxf(m_run[r], mx);
                float f = __expf(m_run[r] - mnew);
                l_run[r] *= f;
                m_run[r] = mnew;
#pragma unroll
                for (int n = 0; n < 8; n++) o_acc[n][r] *= f;
            }
            float rs = 0.f;
            int prow = lq * 4 + r;
            char* pb = Pw + prow * 128;
#pragma unroll
            for (int n = 0; n < 4; n++) {
                float e = __expf(sa[n][r] - m_run[r]);
                rs += e;
                int col = n * 16 + lr;
                *(u16*)(pb + (((col >> 3) ^ (prow & 7)) << 4) + (col & 7) * 2) = f2bf(e);
            }
#pragma unroll
            for (int off = 8; off >= 1; off >>= 1) rs += __shfl_xor(rs, off, 64);
            l_run[r] += rs;
        }

        // O += P V : V fragments straight from global (L2-hit), per-n load+MFMA
        // (per-n form, NOT batched vb8[8]: that spilled in round 4)
#pragma unroll
        for (int kk = 0; kk < 2; kk++) {
            int slot = kk * 4 + lq;
            bf16x8 pa = *(bf16x8*)(Pw + lr * 128 + ((slot ^ (lr & 7)) << 4));
            __builtin_amdgcn_s_setprio(1);
#pragma unroll
            for (int n = 0; n < 8; n++) {
                bf16x8 vb8 = *(const bf16x8*)(Vbase + (size_t)(n * 16 + lr) * S_LEN + kv0 + kk * 32 + lq * 8);
                o_acc[n] = __builtin_amdgcn_mfma_f32_16x16x32_bf16(pa, vb8, o_acc[n], 0, 0, 0);
            }
            __builtin_amdgcn_s_setprio(0);
        }
    }

    // write partials (Om[wv] overwrites this wave's P area only after its last P read)
    __builtin_amdgcn_sched_barrier(0);
#pragma unroll
    for (int n = 0; n < 8; n++)
#pragma unroll
        for (int r = 0; r < 4; r++)
            Om[wv * 2048 + (lq * 4 + r) * 128 + n * 16 + lr] = o_acc[n][r];
    if (lr == 0) {
#pragma unroll
        for (int r = 0; r < 4; r++) {
            ml[wv * 32 + (lq * 4 + r) * 2 + 0] = m_run[r];
            ml[wv * 32 + (lq * 4 + r) * 2 + 1] = l_run[r];
        }
    }
    __syncthreads();

    // merge the 4 partials: thread -> (row = t>>4, cols (t&15)*8 .. +8)
    {
        int row = t >> 4, c0 = (t & 15) * 8;
        float m4[4], l4[4];
#pragma unroll
        for (int w = 0; w < 4; w++) {
            m4[w] = ml[w * 32 + row * 2 + 0];
            l4[w] = ml[w * 32 + row * 2 + 1];
        }
        float ms = fmaxf(fmaxf(m4[0], m4[1]), fmaxf(m4[2], m4[3]));
        float wt[4], ls = 0.f;
#pragma unroll
        for (int w = 0; w < 4; w++) { wt[w] = __expf(m4[w] - ms); ls += l4[w] * wt[w]; }
        float inv = 1.0f / ls;
        f32x4 r0 = (f32x4)0.f, r1 = (f32x4)0.f;
#pragma unroll
        for (int w = 0; w < 4; w++) {
            const f32x4* Op = (const f32x4*)(Om + w * 2048 + row * 128 + c0);
            r0 += Op[0] * wt[w];
            r1 += Op[1] * wt[w];
        }
        f32x4* dst = (f32x4*)(out + (qbase + qr0 + row) * HDIM + c0);
        dst[0] = r0 * inv;
        dst[1] = r1 * inv;
    }
}

extern "C" void kernel_launch(void* const* d_in, const int* in_sizes, int n_in,
                              void* d_out, int out_size, void* d_ws, size_t ws_size,
                              hipStream_t stream) {
    const float* hs = (const float*)d_in[0];
    const float* Wq = (const float*)d_in[1];
    const float* bq = (const float*)d_in[2];
    const float* Wk = (const float*)d_in[3];
    const float* bk = (const float*)d_in[4];
    const float* Wv = (const float*)d_in[5];
    const float* bv = (const float*)d_in[6];
    float* out = (float*)d_out;

    char* ws = (char*)d_ws;
    u16* Qb = (u16*)(ws);                       // 4 MB  [16384][128] bf16 (pre-scaled)
    u16* Kb = (u16*)(ws + (size_t)(4  << 20));  // 4 MB
    u16* Vt = (u16*)(ws + (size_t)(8  << 20));  // 4 MB  [8][128][2048] (written by qkv epilogue)
    u16* Wp = (u16*)(ws + (size_t)(12 << 20));  // 1.5 MB [384][2048]

    hipLaunchKernelGGL(pack_weights, dim3(192), dim3(256), 0, stream, Wq, Wk, Wv, Wp);
    hipLaunchKernelGGL(qkv_gemm, dim3(256), dim3(512), 0, stream, hs, Wp, bq, bk, bv, Qb, Kb, Vt);
    hipLaunchKernelGGL(attn, dim3(1024), dim3(256), 0, stream, Qb, Kb, Vt, out);
}

// Round 14
// 124.737 us; speedup vs baseline: 1.3824x; 1.2873x over previous
//
#include <hip/hip_runtime.h>
#include <hip/hip_bf16.h>
#include <stdint.h>

#define B_DIM 8
#define S_LEN 2048
#define DMODEL 2048
#define HDIM 128

typedef __attribute__((ext_vector_type(4))) float f32x4;
typedef __attribute__((ext_vector_type(8))) short bf16x8;
typedef __attribute__((ext_vector_type(4))) short bf16x4;
typedef __attribute__((ext_vector_type(4))) unsigned int u32x4;
typedef unsigned short u16;
typedef unsigned int u32;

__device__ __forceinline__ u16 f2bf(float f) {
    union { float f; u32 u; } v; v.f = f;
    u32 u = v.u;
    u32 r = (u + 0x7fffu + ((u >> 16) & 1u)) >> 16;
    return (u16)r;
}

__device__ __forceinline__ u32 pk2bf(float a, float b) {
    float2 f2; f2.x = a; f2.y = b;
    __hip_bfloat162 h = __float22bfloat162_rn(f2);
    union { __hip_bfloat162 h; u32 u; } cv; cv.h = h;
    return cv.u;
}

__device__ __forceinline__ void async_copy16(u16* lds, const u16* g) {
    __builtin_amdgcn_global_load_lds((const __attribute__((address_space(1))) u32*)g,
                                     (__attribute__((address_space(3))) u32*)lds,
                                     16, 0, 0);
}

// ---------------- pack weights: transpose [2048 k][128 h] fp32 x3 -> bf16 Wp[384 h][2048 k]
__global__ void pack_weights(const float* __restrict__ Wq, const float* __restrict__ Wk,
                             const float* __restrict__ Wv, u16* __restrict__ Wp) {
    __shared__ u16 tl[64 * 64];
    int t = threadIdx.x;
    int bx = blockIdx.x;                 // 3 w * 32 kt * 2 ht = 192
    int w = bx >> 6;
    int kt = (bx >> 1) & 31;
    int ht = bx & 1;
    int k0 = kt * 64, h0 = ht * 64;
    const float* W = (w == 0) ? Wq : ((w == 1) ? Wk : Wv);

    int kl = t >> 2, hc = t & 3;
    const float* src = W + (size_t)(k0 + kl) * HDIM + h0 + hc * 16;
#pragma unroll
    for (int half = 0; half < 2; half++) {
        bf16x8 p;
#pragma unroll
        for (int j = 0; j < 8; j++) p[j] = (short)f2bf(src[half * 8 + j]);
        int slot = hc * 2 + half;
        *(bf16x8*)((char*)tl + kl * 128 + ((slot ^ (kl & 7)) << 4)) = p;
    }
    __syncthreads();
    int hl = t >> 2, kc = t & 3;
    u16* dst = Wp + (size_t)(w * HDIM + h0 + hl) * DMODEL + k0 + kc * 16;
#pragma unroll
    for (int half = 0; half < 2; half++) {
        bf16x8 p;
#pragma unroll
        for (int j = 0; j < 8; j++) {
            int k = kc * 16 + half * 8 + j;
            p[j] = *(u16*)((char*)tl + k * 128 + (((hl >> 3) ^ (k & 7)) << 4) + (hl & 7) * 2);
        }
        *(bf16x8*)(dst + half * 8) = p;
    }
}

// ---------------- fused QKV projection GEMM: [16384,2048] @ [2048,384] (bf16 MFMA)
// Round-11 structure (best total) + PER-BLOCK K-RING OFFSET: all blocks used to sweep
// the same 1.5MB Wp in lockstep (barriers phase-align them) -> 32 CUs/XCD request the
// SAME L2 lines each phase -> same-bank serialization at the L2. Offset ko gives each
// of an XCD's 32 blocks a different start tile; per-output accumulation order is fixed
// (deterministic). BM=64, BN=384, BK=64, grid 256, 8 waves. vmcnt(2) keeps the 2
// A-prefetch loads in flight across the barrier.
// Ledger: BK=32 bank-conflicts (r8); LDS-free 2x slower (r9); BN=192/2blk-CU null
// (r10); ring-3/4 deeper prefetch null-to-worse (r12/r13). Phase cost is in the L2.
__launch_bounds__(512)
__global__ void qkv_gemm(const float* __restrict__ hs, const u16* __restrict__ Wp,
                         const float* __restrict__ bq, const float* __restrict__ bk,
                         const float* __restrict__ bv,
                         u16* __restrict__ Qb, u16* __restrict__ Kb, u16* __restrict__ Vt) {
    __shared__ u16 As[2][64 * 64];       // 2 x 8 KB, 16B-slot XOR swizzle
    __shared__ u16 Bs[2][384 * 64];      // 2 x 48 KB, swizzled

    int t = threadIdx.x;
    int wv = t >> 6, l = t & 63, lr = l & 15, lq = l >> 4;
    int wm = wv >> 2, wn = wv & 3;
    int m0 = blockIdx.x * 64;
    int ko = ((blockIdx.x >> 3) & 31) << 6;   // k-ring start: unique per block within an XCD

#define KW(X) (((X) + ko) & (DMODEL - 1))

    f32x4 acc[2][6] = {};

    int ar = t >> 3, aq = t & 7;         // A staging: row 0..63, 8-float chunk 0..7
    const float* gA = hs + (size_t)(m0 + ar) * DMODEL + aq * 8;

    f32x4 p0A, p1A, p0B, p1B;            // two A-prefetch register sets (depth 2)

#define STAGE_B(K0, BUF)                                                    \
    {                                                                       \
        _Pragma("unroll")                                                   \
        for (int i = 0; i < 6; i++) {                                       \
            int c = i * 512 + t;                                            \
            int n = c >> 3, s = c & 7;                                      \
            async_copy16(&Bs[BUF][c * 8],                                   \
                         Wp + (size_t)n * DMODEL + (K0) + ((s ^ (n & 7)) * 8)); \
        }                                                                   \
    }
#define WRITE_A(BUF, V0, V1)                                                \
    {                                                                       \
        u32x4 pk;                                                           \
        pk.x = pk2bf(V0[0], V0[1]); pk.y = pk2bf(V0[2], V0[3]);             \
        pk.z = pk2bf(V1[0], V1[1]); pk.w = pk2bf(V1[2], V1[3]);             \
        *(u32x4*)((char*)&As[BUF][0] + ar * 128 + ((aq ^ (ar & 7)) << 4)) = pk; \
    }
#define COMPUTE(CUR)                                                        \
    {                                                                       \
        _Pragma("unroll")                                                   \
        for (int kk = 0; kk < 2; kk++) {                                    \
            bf16x8 afr[2], bfr[6];                                          \
            int slot = kk * 4 + lq;                                         \
            _Pragma("unroll")                                               \
            for (int mi = 0; mi < 2; mi++) {                                \
                int row = wm * 32 + mi * 16 + lr;                           \
                afr[mi] = *(bf16x8*)((char*)&As[CUR][0] + row * 128 + ((slot ^ (row & 7)) << 4)); \
            }                                                               \
            _Pragma("unroll")                                               \
            for (int ni = 0; ni < 6; ni++) {                                \
                int row = wn * 96 + ni * 16 + lr;                           \
                bfr[ni] = *(bf16x8*)((char*)&Bs[CUR][0] + row * 128 + ((slot ^ (row & 7)) << 4)); \
            }                                                               \
            __builtin_amdgcn_s_setprio(1);                                  \
            _Pragma("unroll")                                               \
            for (int mi = 0; mi < 2; mi++)                                  \
                _Pragma("unroll")                                           \
                for (int ni = 0; ni < 6; ni++)                              \
                    acc[mi][ni] = __builtin_amdgcn_mfma_f32_16x16x32_bf16(afr[mi], bfr[ni], acc[mi][ni], 0, 0, 0); \
            __builtin_amdgcn_s_setprio(0);                                  \
        }                                                                   \
    }
#define SYNC_PIPE                                                           \
    asm volatile("s_waitcnt vmcnt(2) lgkmcnt(0)" ::: "memory");             \
    __builtin_amdgcn_sched_barrier(0);                                      \
    __builtin_amdgcn_s_barrier();                                           \
    __builtin_amdgcn_sched_barrier(0);

    // prologue: tile ko into buf0; prefetch A(ko+64)
    p0A = *(const f32x4*)(gA + KW(0)); p1A = *(const f32x4*)(gA + KW(0) + 4);
    STAGE_B(KW(0), 0);
    WRITE_A(0, p0A, p1A);
    p0A = *(const f32x4*)(gA + KW(64)); p1A = *(const f32x4*)(gA + KW(64) + 4);
    __syncthreads();                     // full drain once (prologue only)

    for (int k0 = 0; k0 < DMODEL; k0 += 128) {
        // even step: compute buf0; stage tile(i+1)->buf1; prefetch A(i+2)
        {
            int ks = KW(k0 + 64);
            int kp = KW(k0 + 128);
            STAGE_B(ks, 1);
            p0B = *(const f32x4*)(gA + kp); p1B = *(const f32x4*)(gA + kp + 4);
            COMPUTE(0);
            WRITE_A(1, p0A, p1A);
            SYNC_PIPE
        }
        // odd step: compute buf1; stage->buf0; prefetch
        {
            int ks = KW(k0 + 128);
            int kp = KW(k0 + 192);
            STAGE_B(ks, 0);
            p0A = *(const f32x4*)(gA + kp); p1A = *(const f32x4*)(gA + kp + 4);
            COMPUTE(1);
            WRITE_A(0, p0B, p1B);
            SYNC_PIPE
        }
    }

    // epilogue: bias; Q pre-scaled by 1/sqrt(128); V written transposed to Vt[b][h][s]
#pragma unroll
    for (int ni = 0; ni < 6; ni++) {
        int col = wn * 96 + ni * 16 + lr;
        int w = col >> 7, h = col & 127;
        const float* bp = (w == 0) ? bq : ((w == 1) ? bk : bv);
        float bias = bp[h];
#pragma unroll
        for (int mi = 0; mi < 2; mi++) {
            int row0 = m0 + wm * 32 + mi * 16 + lq * 4;
            if (w == 2) {
                int b = row0 >> 11, s0 = row0 & (S_LEN - 1);
                bf16x4 pv;
#pragma unroll
                for (int r = 0; r < 4; r++) pv[r] = (short)f2bf(acc[mi][ni][r] + bias);
                *(bf16x4*)(Vt + (size_t)(b * HDIM + h) * S_LEN + s0) = pv;
            } else {
                float scale = (w == 0) ? 0.08838834764831845f : 1.0f;
                u16* dst = (w == 0) ? Qb : Kb;
#pragma unroll
                for (int r = 0; r < 4; r++)
                    dst[(size_t)(row0 + r) * HDIM + h] = f2bf((acc[mi][ni][r] + bias) * scale);
            }
        }
    }
#undef STAGE_B
#undef WRITE_A
#undef COMPUTE
#undef SYNC_PIPE
#undef KW
}

// ---------------- causal flash attention: 4 waves per block split the KV range of ONE
// 16-row Q tile (kt = wv, wv+4, ...); no barriers in main loop; LDS merge at the end.
// launch_bounds(256,3): 3 waves/EU -> ~170-reg unified cap. (256,4) capped at 128 and
// SPILLED (rounds 4-6: VGPR=64 + 23MB scratch writes). Do not raise to 4.
// Defer-max (T13, THR=8): skip the exp+rescale of o_acc unless the tile max exceeds
// the running max by >8; P values bounded by e^8.
__launch_bounds__(256, 3)
__global__ void attn(const u16* __restrict__ Qb, const u16* __restrict__ Kb,
                     const u16* __restrict__ Vt, float* __restrict__ out) {
    __shared__ char lds[33280];          // Om[4][16][128] f32 (32768) + ml[4][16][2] f32 (512)
    float* Om = (float*)lds;
    float* ml = (float*)(lds + 32768);

    int t = threadIdx.x;
    int wv = t >> 6, l = t & 63, lr = l & 15, lq = l >> 4;
    int bx = blockIdx.x;                 // 1024 = 8 b x 128 qt
    int b = bx & 7;                      // batch == XCD for KV L2 locality
    int qt = 127 - (bx >> 3);            // descending work order
    int qr0 = qt * 16;
    size_t qbase = (size_t)b * S_LEN;
    char* Pw = lds + wv * 8192;          // P tile aliases this wave's own Om region

    bf16x8 aqf[4];
#pragma unroll
    for (int kk = 0; kk < 4; kk++)
        aqf[kk] = *(const bf16x8*)(Qb + (qbase + qr0 + lr) * HDIM + kk * 32 + lq * 8);

    f32x4 o_acc[8] = {};
    float m_run[4], l_run[4];
#pragma unroll
    for (int r = 0; r < 4; r++) { m_run[r] = -1e38f; l_run[r] = 0.f; }

    int ktd = qt >> 2;                   // diagonal 64-wide tile index
    const u16* Kbase = Kb + qbase * HDIM;
    const u16* Vbase = Vt + (size_t)b * HDIM * S_LEN;

    for (int kt = wv; kt <= ktd; kt += 4) {
        int kv0 = kt * 64;

        // S = Q K^T : K fragments straight from global (L2-hit)
        f32x4 sa[4] = {};
#pragma unroll
        for (int kk = 0; kk < 4; kk++) {
            bf16x8 bk8[4];
#pragma unroll
            for (int n = 0; n < 4; n++)
                bk8[n] = *(const bf16x8*)(Kbase + (size_t)(kv0 + n * 16 + lr) * HDIM + kk * 32 + lq * 8);
            __builtin_amdgcn_s_setprio(1);
#pragma unroll
            for (int n = 0; n < 4; n++)
                sa[n] = __builtin_amdgcn_mfma_f32_16x16x32_bf16(aqf[kk], bk8[n], sa[n], 0, 0, 0);
            __builtin_amdgcn_s_setprio(0);
        }

        if (kt == ktd) {                 // causal mask on the diagonal tile
#pragma unroll
            for (int n = 0; n < 4; n++) {
                int col = kv0 + n * 16 + lr;
#pragma unroll
                for (int r = 0; r < 4; r++) {
                    int row = qr0 + lq * 4 + r;
                    if (col > row) sa[n][r] = -1e30f;
                }
            }
        }

        // online softmax with defer-max (16-lane groups own 4 q-rows each)
#pragma unroll
        for (int r = 0; r < 4; r++) {
            float mx = fmaxf(fmaxf(sa[0][r], sa[1][r]), fmaxf(sa[2][r], sa[3][r]));
#pragma unroll
            for (int off = 8; off >= 1; off >>= 1) mx = fmaxf(mx, __shfl_xor(mx, off, 64));
            if (__any(mx > m_run[r] + 8.0f)) {   // wave-uniform branch (ballot)
                float mnew = fmaxf(m_run[r], mx);
                float f = __expf(m_run[r] - mnew);
                l_run[r] *= f;
                m_run[r] = mnew;
#pragma unroll
                for (int n = 0; n < 8; n++) o_acc[n][r] *= f;
            }
            float rs = 0.f;
            int prow = lq * 4 + r;
            char* pb = Pw + prow * 128;
#pragma unroll
            for (int n = 0; n < 4; n++) {
                float e = __expf(sa[n][r] - m_run[r]);
                rs += e;
                int col = n * 16 + lr;
                *(u16*)(pb + (((col >> 3) ^ (prow & 7)) << 4) + (col & 7) * 2) = f2bf(e);
            }
#pragma unroll
            for (int off = 8; off >= 1; off >>= 1) rs += __shfl_xor(rs, off, 64);
            l_run[r] += rs;
        }

        // O += P V : V fragments straight from global (L2-hit), per-n load+MFMA
        // (per-n form, NOT batched vb8[8]: that spilled in round 4)
#pragma unroll
        for (int kk = 0; kk < 2; kk++) {
            int slot = kk * 4 + lq;
            bf16x8 pa = *(bf16x8*)(Pw + lr * 128 + ((slot ^ (lr & 7)) << 4));
            __builtin_amdgcn_s_setprio(1);
#pragma unroll
            for (int n = 0; n < 8; n++) {
                bf16x8 vb8 = *(const bf16x8*)(Vbase + (size_t)(n * 16 + lr) * S_LEN + kv0 + kk * 32 + lq * 8);
                o_acc[n] = __builtin_amdgcn_mfma_f32_16x16x32_bf16(pa, vb8, o_acc[n], 0, 0, 0);
            }
            __builtin_amdgcn_s_setprio(0);
        }
    }

    // write partials (Om[wv] overwrites this wave's P area only after its last P read)
    __builtin_amdgcn_sched_barrier(0);
#pragma unroll
    for (int n = 0; n < 8; n++)
#pragma unroll
        for (int r = 0; r < 4; r++)
            Om[wv * 2048 + (lq * 4 + r) * 128 + n * 16 + lr] = o_acc[n][r];
    if (lr == 0) {
#pragma unroll
        for (int r = 0; r < 4; r++) {
            ml[wv * 32 + (lq * 4 + r) * 2 + 0] = m_run[r];
            ml[wv * 32 + (lq * 4 + r) * 2 + 1] = l_run[r];
        }
    }
    __syncthreads();

    // merge the 4 partials: thread -> (row = t>>4, cols (t&15)*8 .. +8)
    {
        int row = t >> 4, c0 = (t & 15) * 8;
        float m4[4], l4[4];
#pragma unroll
        for (int w = 0; w < 4; w++) {
            m4[w] = ml[w * 32 + row * 2 + 0];
            l4[w] = ml[w * 32 + row * 2 + 1];
        }
        float ms = fmaxf(fmaxf(m4[0], m4[1]), fmaxf(m4[2], m4[3]));
        float wt[4], ls = 0.f;
#pragma unroll
        for (int w = 0; w < 4; w++) { wt[w] = __expf(m4[w] - ms); ls += l4[w] * wt[w]; }
        float inv = 1.0f / ls;
        f32x4 r0 = (f32x4)0.f, r1 = (f32x4)0.f;
#pragma unroll
        for (int w = 0; w < 4; w++) {
            const f32x4* Op = (const f32x4*)(Om + w * 2048 + row * 128 + c0);
            r0 += Op[0] * wt[w];
            r1 += Op[1] * wt[w];
        }
        f32x4* dst = (f32x4*)(out + (qbase + qr0 + row) * HDIM + c0);
        dst[0] = r0 * inv;
        dst[1] = r1 * inv;
    }
}

extern "C" void kernel_launch(void* const* d_in, const int* in_sizes, int n_in,
                              void* d_out, int out_size, void* d_ws, size_t ws_size,
                              hipStream_t stream) {
    const float* hs = (const float*)d_in[0];
    const float* Wq = (const float*)d_in[1];
    const float* bq = (const float*)d_in[2];
    const float* Wk = (const float*)d_in[3];
    const float* bk = (const float*)d_in[4];
    const float* Wv = (const float*)d_in[5];
    const float* bv = (const float*)d_in[6];
    float* out = (float*)d_out;

    char* ws = (char*)d_ws;
    u16* Qb = (u16*)(ws);                       // 4 MB  [16384][128] bf16 (pre-scaled)
    u16* Kb = (u16*)(ws + (size_t)(4  << 20));  // 4 MB
    u16* Vt = (u16*)(ws + (size_t)(8  << 20));  // 4 MB  [8][128][2048] (written by qkv epilogue)
    u16* Wp = (u16*)(ws + (size_t)(12 << 20));  // 1.5 MB [384][2048]

    hipLaunchKernelGGL(pack_weights, dim3(192), dim3(256), 0, stream, Wq, Wk, Wv, Wp);
    hipLaunchKernelGGL(qkv_gemm, dim3(256), dim3(512), 0, stream, hs, Wp, bq, bk, bv, Qb, Kb, Vt);
    hipLaunchKernelGGL(attn, dim3(1024), dim3(256), 0, stream, Qb, Kb, Vt, out);
}

// Round 15
// 123.830 us; speedup vs baseline: 1.3925x; 1.0073x over previous
//
#include <hip/hip_runtime.h>
#include <hip/hip_bf16.h>
#include <stdint.h>

#define B_DIM 8
#define S_LEN 2048
#define DMODEL 2048
#define HDIM 128

typedef __attribute__((ext_vector_type(4))) float f32x4;
typedef __attribute__((ext_vector_type(8))) short bf16x8;
typedef __attribute__((ext_vector_type(4))) short bf16x4;
typedef __attribute__((ext_vector_type(4))) unsigned int u32x4;
typedef unsigned short u16;
typedef unsigned int u32;

__device__ __forceinline__ u16 f2bf(float f) {
    union { float f; u32 u; } v; v.f = f;
    u32 u = v.u;
    u32 r = (u + 0x7fffu + ((u >> 16) & 1u)) >> 16;
    return (u16)r;
}

__device__ __forceinline__ u32 pk2bf(float a, float b) {
    float2 f2; f2.x = a; f2.y = b;
    __hip_bfloat162 h = __float22bfloat162_rn(f2);
    union { __hip_bfloat162 h; u32 u; } cv; cv.h = h;
    return cv.u;
}

__device__ __forceinline__ void async_copy16(u16* lds, const u16* g) {
    __builtin_amdgcn_global_load_lds((const __attribute__((address_space(1))) u32*)g,
                                     (__attribute__((address_space(3))) u32*)lds,
                                     16, 0, 0);
}

// ---------------- pack weights: transpose [2048 k][128 h] fp32 x3 -> bf16 Wp[384 h][2048 k]
__global__ void pack_weights(const float* __restrict__ Wq, const float* __restrict__ Wk,
                             const float* __restrict__ Wv, u16* __restrict__ Wp) {
    __shared__ u16 tl[64 * 64];
    int t = threadIdx.x;
    int bx = blockIdx.x;                 // 3 w * 32 kt * 2 ht = 192
    int w = bx >> 6;
    int kt = (bx >> 1) & 31;
    int ht = bx & 1;
    int k0 = kt * 64, h0 = ht * 64;
    const float* W = (w == 0) ? Wq : ((w == 1) ? Wk : Wv);

    int kl = t >> 2, hc = t & 3;
    const float* src = W + (size_t)(k0 + kl) * HDIM + h0 + hc * 16;
#pragma unroll
    for (int half = 0; half < 2; half++) {
        bf16x8 p;
#pragma unroll
        for (int j = 0; j < 8; j++) p[j] = (short)f2bf(src[half * 8 + j]);
        int slot = hc * 2 + half;
        *(bf16x8*)((char*)tl + kl * 128 + ((slot ^ (kl & 7)) << 4)) = p;
    }
    __syncthreads();
    int hl = t >> 2, kc = t & 3;
    u16* dst = Wp + (size_t)(w * HDIM + h0 + hl) * DMODEL + k0 + kc * 16;
#pragma unroll
    for (int half = 0; half < 2; half++) {
        bf16x8 p;
#pragma unroll
        for (int j = 0; j < 8; j++) {
            int k = kc * 16 + half * 8 + j;
            p[j] = *(u16*)((char*)tl + k * 128 + (((hl >> 3) ^ (k & 7)) << 4) + (hl & 7) * 2);
        }
        *(bf16x8*)(dst + half * 8) = p;
    }
}

// ---------------- fused QKV projection GEMM: [16384,2048] @ [2048,384] (bf16 MFMA)
// Round-14 kernel (best total): r11 structure + per-block k-ring offset (L2 hotspot
// de-phasing; +3.6us total). BM=64, BN=384, BK=64, grid 256, 8 waves. vmcnt(2) keeps
// the 2 A-prefetch loads in flight across the barrier. V written transposed.
// Ledger: BK=32 bank-conflicts (r8); LDS-free 2x slower (r9); BN=192/2blk-CU null
// (r10); ring-3/4 deeper prefetch null-to-worse (r12/r13). FROZEN.
__launch_bounds__(512)
__global__ void qkv_gemm(const float* __restrict__ hs, const u16* __restrict__ Wp,
                         const float* __restrict__ bq, const float* __restrict__ bk,
                         const float* __restrict__ bv,
                         u16* __restrict__ Qb, u16* __restrict__ Kb, u16* __restrict__ Vt) {
    __shared__ u16 As[2][64 * 64];       // 2 x 8 KB, 16B-slot XOR swizzle
    __shared__ u16 Bs[2][384 * 64];      // 2 x 48 KB, swizzled

    int t = threadIdx.x;
    int wv = t >> 6, l = t & 63, lr = l & 15, lq = l >> 4;
    int wm = wv >> 2, wn = wv & 3;
    int m0 = blockIdx.x * 64;
    int ko = ((blockIdx.x >> 3) & 31) << 6;   // k-ring start: unique per block within an XCD

#define KW(X) (((X) + ko) & (DMODEL - 1))

    f32x4 acc[2][6] = {};

    int ar = t >> 3, aq = t & 7;         // A staging: row 0..63, 8-float chunk 0..7
    const float* gA = hs + (size_t)(m0 + ar) * DMODEL + aq * 8;

    f32x4 p0A, p1A, p0B, p1B;            // two A-prefetch register sets (depth 2)

#define STAGE_B(K0, BUF)                                                    \
    {                                                                       \
        _Pragma("unroll")                                                   \
        for (int i = 0; i < 6; i++) {                                       \
            int c = i * 512 + t;                                            \
            int n = c >> 3, s = c & 7;                                      \
            async_copy16(&Bs[BUF][c * 8],                                   \
                         Wp + (size_t)n * DMODEL + (K0) + ((s ^ (n & 7)) * 8)); \
        }                                                                   \
    }
#define WRITE_A(BUF, V0, V1)                                                \
    {                                                                       \
        u32x4 pk;                                                           \
        pk.x = pk2bf(V0[0], V0[1]); pk.y = pk2bf(V0[2], V0[3]);             \
        pk.z = pk2bf(V1[0], V1[1]); pk.w = pk2bf(V1[2], V1[3]);             \
        *(u32x4*)((char*)&As[BUF][0] + ar * 128 + ((aq ^ (ar & 7)) << 4)) = pk; \
    }
#define COMPUTE(CUR)                                                        \
    {                                                                       \
        _Pragma("unroll")                                                   \
        for (int kk = 0; kk < 2; kk++) {                                    \
            bf16x8 afr[2], bfr[6];                                          \
            int slot = kk * 4 + lq;                                         \
            _Pragma("unroll")                                               \
            for (int mi = 0; mi < 2; mi++) {                                \
                int row = wm * 32 + mi * 16 + lr;                           \
                afr[mi] = *(bf16x8*)((char*)&As[CUR][0] + row * 128 + ((slot ^ (row & 7)) << 4)); \
            }                                                               \
            _Pragma("unroll")                                               \
            for (int ni = 0; ni < 6; ni++) {                                \
                int row = wn * 96 + ni * 16 + lr;                           \
                bfr[ni] = *(bf16x8*)((char*)&Bs[CUR][0] + row * 128 + ((slot ^ (row & 7)) << 4)); \
            }                                                               \
            __builtin_amdgcn_s_setprio(1);                                  \
            _Pragma("unroll")                                               \
            for (int mi = 0; mi < 2; mi++)                                  \
                _Pragma("unroll")                                           \
                for (int ni = 0; ni < 6; ni++)                              \
                    acc[mi][ni] = __builtin_amdgcn_mfma_f32_16x16x32_bf16(afr[mi], bfr[ni], acc[mi][ni], 0, 0, 0); \
            __builtin_amdgcn_s_setprio(0);                                  \
        }                                                                   \
    }
#define SYNC_PIPE                                                           \
    asm volatile("s_waitcnt vmcnt(2) lgkmcnt(0)" ::: "memory");             \
    __builtin_amdgcn_sched_barrier(0);                                      \
    __builtin_amdgcn_s_barrier();                                           \
    __builtin_amdgcn_sched_barrier(0);

    // prologue: tile ko into buf0; prefetch A(ko+64)
    p0A = *(const f32x4*)(gA + KW(0)); p1A = *(const f32x4*)(gA + KW(0) + 4);
    STAGE_B(KW(0), 0);
    WRITE_A(0, p0A, p1A);
    p0A = *(const f32x4*)(gA + KW(64)); p1A = *(const f32x4*)(gA + KW(64) + 4);
    __syncthreads();                     // full drain once (prologue only)

    for (int k0 = 0; k0 < DMODEL; k0 += 128) {
        // even step: compute buf0; stage tile(i+1)->buf1; prefetch A(i+2)
        {
            int ks = KW(k0 + 64);
            int kp = KW(k0 + 128);
            STAGE_B(ks, 1);
            p0B = *(const f32x4*)(gA + kp); p1B = *(const f32x4*)(gA + kp + 4);
            COMPUTE(0);
            WRITE_A(1, p0A, p1A);
            SYNC_PIPE
        }
        // odd step: compute buf1; stage->buf0; prefetch
        {
            int ks = KW(k0 + 128);
            int kp = KW(k0 + 192);
            STAGE_B(ks, 0);
            p0A = *(const f32x4*)(gA + kp); p1A = *(const f32x4*)(gA + kp + 4);
            COMPUTE(1);
            WRITE_A(0, p0B, p1B);
            SYNC_PIPE
        }
    }

    // epilogue: bias; Q pre-scaled by 1/sqrt(128); V written transposed to Vt[b][h][s]
#pragma unroll
    for (int ni = 0; ni < 6; ni++) {
        int col = wn * 96 + ni * 16 + lr;
        int w = col >> 7, h = col & 127;
        const float* bp = (w == 0) ? bq : ((w == 1) ? bk : bv);
        float bias = bp[h];
#pragma unroll
        for (int mi = 0; mi < 2; mi++) {
            int row0 = m0 + wm * 32 + mi * 16 + lq * 4;
            if (w == 2) {
                int b = row0 >> 11, s0 = row0 & (S_LEN - 1);
                bf16x4 pv;
#pragma unroll
                for (int r = 0; r < 4; r++) pv[r] = (short)f2bf(acc[mi][ni][r] + bias);
                *(bf16x4*)(Vt + (size_t)(b * HDIM + h) * S_LEN + s0) = pv;
            } else {
                float scale = (w == 0) ? 0.08838834764831845f : 1.0f;
                u16* dst = (w == 0) ? Qb : Kb;
#pragma unroll
                for (int r = 0; r < 4; r++)
                    dst[(size_t)(row0 + r) * HDIM + h] = f2bf((acc[mi][ni][r] + bias) * scale);
            }
        }
    }
#undef STAGE_B
#undef WRITE_A
#undef COMPUTE
#undef SYNC_PIPE
#undef KW
}

// ---------------- causal flash attention: 4 waves per block split the KV range of ONE
// 16-row Q tile (kt = wv, wv+4, ...); no barriers in main loop; LDS merge at the end.
// launch_bounds(256,3): (256,4) caps regs at 128 and SPILLED (r4-6). Do not raise.
// Defer-max (T13, THR=8) + SHUFFLE-FREE COMMON PATH (r14->r15):
//  - threshold check via __any on PER-LANE partial max (ballot == reduce-then-compare;
//    the full 4-shuffle max-reduce moved inside the rare rescale branch)
//  - l_run kept as PER-LANE PARTIAL (no per-tile sum shuffles; scales linearly under
//    rescale); ONE 4-shuffle reduce after the kt loop.
// Removes all 32 cross-lane ops/tile from the QK^T->PV critical path.
__launch_bounds__(256, 3)
__global__ void attn(const u16* __restrict__ Qb, const u16* __restrict__ Kb,
                     const u16* __restrict__ Vt, float* __restrict__ out) {
    __shared__ char lds[33280];          // Om[4][16][128] f32 (32768) + ml[4][16][2] f32 (512)
    float* Om = (float*)lds;
    float* ml = (float*)(lds + 32768);

    int t = threadIdx.x;
    int wv = t >> 6, l = t & 63, lr = l & 15, lq = l >> 4;
    int bx = blockIdx.x;                 // 1024 = 8 b x 128 qt
    int b = bx & 7;                      // batch == XCD for KV L2 locality
    int qt = 127 - (bx >> 3);            // descending work order
    int qr0 = qt * 16;
    size_t qbase = (size_t)b * S_LEN;
    char* Pw = lds + wv * 8192;          // P tile aliases this wave's own Om region

    bf16x8 aqf[4];
#pragma unroll
    for (int kk = 0; kk < 4; kk++)
        aqf[kk] = *(const bf16x8*)(Qb + (qbase + qr0 + lr) * HDIM + kk * 32 + lq * 8);

    f32x4 o_acc[8] = {};
    float m_run[4], l_run[4];
#pragma unroll
    for (int r = 0; r < 4; r++) { m_run[r] = -1e38f; l_run[r] = 0.f; }

    int ktd = qt >> 2;                   // diagonal 64-wide tile index
    const u16* Kbase = Kb + qbase * HDIM;
    const u16* Vbase = Vt + (size_t)b * HDIM * S_LEN;

    for (int kt = wv; kt <= ktd; kt += 4) {
        int kv0 = kt * 64;

        // S = Q K^T : K fragments straight from global (L2-hit)
        f32x4 sa[4] = {};
#pragma unroll
        for (int kk = 0; kk < 4; kk++) {
            bf16x8 bk8[4];
#pragma unroll
            for (int n = 0; n < 4; n++)
                bk8[n] = *(const bf16x8*)(Kbase + (size_t)(kv0 + n * 16 + lr) * HDIM + kk * 32 + lq * 8);
            __builtin_amdgcn_s_setprio(1);
#pragma unroll
            for (int n = 0; n < 4; n++)
                sa[n] = __builtin_amdgcn_mfma_f32_16x16x32_bf16(aqf[kk], bk8[n], sa[n], 0, 0, 0);
            __builtin_amdgcn_s_setprio(0);
        }

        if (kt == ktd) {                 // causal mask on the diagonal tile
#pragma unroll
            for (int n = 0; n < 4; n++) {
                int col = kv0 + n * 16 + lr;
#pragma unroll
                for (int r = 0; r < 4; r++) {
                    int row = qr0 + lq * 4 + r;
                    if (col > row) sa[n][r] = -1e30f;
                }
            }
        }

        // shuffle-free online softmax (16-lane groups own 4 q-rows each)
#pragma unroll
        for (int r = 0; r < 4; r++) {
            float pmx = fmaxf(fmaxf(sa[0][r], sa[1][r]), fmaxf(sa[2][r], sa[3][r]));
            if (__any(pmx > m_run[r] + 8.0f)) {      // rare, wave-uniform
                float mx = pmx;
#pragma unroll
                for (int off = 8; off >= 1; off >>= 1) mx = fmaxf(mx, __shfl_xor(mx, off, 64));
                float mnew = fmaxf(m_run[r], mx);
                float f = __expf(m_run[r] - mnew);
                l_run[r] *= f;                       // per-lane partial scales linearly
                m_run[r] = mnew;
#pragma unroll
                for (int n = 0; n < 8; n++) o_acc[n][r] *= f;
            }
            int prow = lq * 4 + r;
            char* pb = Pw + prow * 128;
#pragma unroll
            for (int n = 0; n < 4; n++) {
                float e = __expf(sa[n][r] - m_run[r]);
                l_run[r] += e;                       // per-lane partial, no shuffles
                int col = n * 16 + lr;
                *(u16*)(pb + (((col >> 3) ^ (prow & 7)) << 4) + (col & 7) * 2) = f2bf(e);
            }
        }

        // O += P V : V fragments straight from global (L2-hit), per-n load+MFMA
        // (per-n form, NOT batched vb8[8]: that spilled in round 4)
#pragma unroll
        for (int kk = 0; kk < 2; kk++) {
            int slot = kk * 4 + lq;
            bf16x8 pa = *(bf16x8*)(Pw + lr * 128 + ((slot ^ (lr & 7)) << 4));
            __builtin_amdgcn_s_setprio(1);
#pragma unroll
            for (int n = 0; n < 8; n++) {
                bf16x8 vb8 = *(const bf16x8*)(Vbase + (size_t)(n * 16 + lr) * S_LEN + kv0 + kk * 32 + lq * 8);
                o_acc[n] = __builtin_amdgcn_mfma_f32_16x16x32_bf16(pa, vb8, o_acc[n], 0, 0, 0);
            }
            __builtin_amdgcn_s_setprio(0);
        }
    }

    // fold the per-lane l partials into group sums (once, not per tile)
#pragma unroll
    for (int r = 0; r < 4; r++) {
#pragma unroll
        for (int off = 8; off >= 1; off >>= 1) l_run[r] += __shfl_xor(l_run[r], off, 64);
    }

    // write partials (Om[wv] overwrites this wave's P area only after its last P read)
    __builtin_amdgcn_sched_barrier(0);
#pragma unroll
    for (int n = 0; n < 8; n++)
#pragma unroll
        for (int r = 0; r < 4; r++)
            Om[wv * 2048 + (lq * 4 + r) * 128 + n * 16 + lr] = o_acc[n][r];
    if (lr == 0) {
#pragma unroll
        for (int r = 0; r < 4; r++) {
            ml[wv * 32 + (lq * 4 + r) * 2 + 0] = m_run[r];
            ml[wv * 32 + (lq * 4 + r) * 2 + 1] = l_run[r];
        }
    }
    __syncthreads();

    // merge the 4 partials: thread -> (row = t>>4, cols (t&15)*8 .. +8)
    {
        int row = t >> 4, c0 = (t & 15) * 8;
        float m4[4], l4[4];
#pragma unroll
        for (int w = 0; w < 4; w++) {
            m4[w] = ml[w * 32 + row * 2 + 0];
            l4[w] = ml[w * 32 + row * 2 + 1];
        }
        float ms = fmaxf(fmaxf(m4[0], m4[1]), fmaxf(m4[2], m4[3]));
        float wt[4], ls = 0.f;
#pragma unroll
        for (int w = 0; w < 4; w++) { wt[w] = __expf(m4[w] - ms); ls += l4[w] * wt[w]; }
        float inv = 1.0f / ls;
        f32x4 r0 = (f32x4)0.f, r1 = (f32x4)0.f;
#pragma unroll
        for (int w = 0; w < 4; w++) {
            const f32x4* Op = (const f32x4*)(Om + w * 2048 + row * 128 + c0);
            r0 += Op[0] * wt[w];
            r1 += Op[1] * wt[w];
        }
        f32x4* dst = (f32x4*)(out + (qbase + qr0 + row) * HDIM + c0);
        dst[0] = r0 * inv;
        dst[1] = r1 * inv;
    }
}

extern "C" void kernel_launch(void* const* d_in, const int* in_sizes, int n_in,
                              void* d_out, int out_size, void* d_ws, size_t ws_size,
                              hipStream_t stream) {
    const float* hs = (const float*)d_in[0];
    const float* Wq = (const float*)d_in[1];
    const float* bq = (const float*)d_in[2];
    const float* Wk = (const float*)d_in[3];
    const float* bk = (const float*)d_in[4];
    const float* Wv = (const float*)d_in[5];
    const float* bv = (const float*)d_in[6];
    float* out = (float*)d_out;

    char* ws = (char*)d_ws;
    u16* Qb = (u16*)(ws);                       // 4 MB  [16384][128] bf16 (pre-scaled)
    u16* Kb = (u16*)(ws + (size_t)(4  << 20));  // 4 MB
    u16* Vt = (u16*)(ws + (size_t)(8  << 20));  // 4 MB  [8][128][2048] (written by qkv epilogue)
    u16* Wp = (u16*)(ws + (size_t)(12 << 20));  // 1.5 MB [384][2048]

    hipLaunchKernelGGL(pack_weights, dim3(192), dim3(256), 0, stream, Wq, Wk, Wv, Wp);
    hipLaunchKernelGGL(qkv_gemm, dim3(256), dim3(512), 0, stream, hs, Wp, bq, bk, bv, Qb, Kb, Vt);
    hipLaunchKernelGGL(attn, dim3(1024), dim3(256), 0, stream, Qb, Kb, Vt, out);
}